// Round 1
// baseline (3450.146 us; speedup 1.0000x reference)
//
#include <hip/hip_runtime.h>

#define BATCH 2
#define SEQ 2048
#define EMBED 2048
#define NHEADS 32
#define NKV 8
#define HDIM 64
// tokens = BATCH*SEQ = 4096

// ---------------- GEMM: C[M,N] = A[M,Kd] * B[N,Kd]^T (fp32) ----------------
#define BM 64
#define BN 64
#define BK 16

__global__ __launch_bounds__(256) void gemm_nt(const float* __restrict__ A,
                                               const float* __restrict__ Bw,
                                               float* __restrict__ C,
                                               int M, int N, int Kd) {
  __shared__ float As[BM][BK + 4];  // row stride 20 floats = 80B (16B aligned)
  __shared__ float Bs[BN][BK + 4];
  const int tid = threadIdx.x;
  const int tx = tid & 15, ty = tid >> 4;
  const int rowBase = blockIdx.y * BM;
  const int colBase = blockIdx.x * BN;
  const int lr = tid >> 2;          // 0..63 tile row for staging
  const int lc = (tid & 3) << 2;    // 0,4,8,12 tile col for staging
  float acc[4][4] = {};
  for (int k0 = 0; k0 < Kd; k0 += BK) {
    float4 av = *(const float4*)&A[(size_t)(rowBase + lr) * Kd + k0 + lc];
    float4 bv = *(const float4*)&Bw[(size_t)(colBase + lr) * Kd + k0 + lc];
    __syncthreads();  // previous iteration's reads done before overwrite
    *(float4*)&As[lr][lc] = av;
    *(float4*)&Bs[lr][lc] = bv;
    __syncthreads();
#pragma unroll
    for (int kk = 0; kk < BK; kk += 4) {
      float4 a4[4], b4[4];
#pragma unroll
      for (int i = 0; i < 4; i++) a4[i] = *(float4*)&As[ty * 4 + i][kk];
#pragma unroll
      for (int j = 0; j < 4; j++) b4[j] = *(float4*)&Bs[tx * 4 + j][kk];
#pragma unroll
      for (int i = 0; i < 4; i++)
#pragma unroll
        for (int j = 0; j < 4; j++)
          acc[i][j] += a4[i].x * b4[j].x + a4[i].y * b4[j].y +
                       a4[i].z * b4[j].z + a4[i].w * b4[j].w;
    }
  }
#pragma unroll
  for (int i = 0; i < 4; i++) {
    size_t r = (size_t)(rowBase + ty * 4 + i);
#pragma unroll
    for (int j = 0; j < 4; j++)
      C[r * N + colBase + tx * 4 + j] = acc[i][j];
  }
}

// ---------------- RoPE (in place), rotate_half convention ----------------
// t layout: (token, head, d) with token = b*SEQ + s. One thread per (token,head,i<32).
__global__ void rope_kernel(float* __restrict__ t, const float* __restrict__ fc,
                            const float* __restrict__ fs, int nHeads, int total) {
  int idx = blockIdx.x * blockDim.x + threadIdx.x;
  if (idx >= total) return;
  int i = idx & 31;
  int h = (idx >> 5) % nHeads;
  int tok = idx / (32 * nHeads);
  int s = tok & (SEQ - 1);
  float* p = t + ((size_t)tok * nHeads + h) * HDIM;
  float x0 = p[i], x1 = p[i + 32];
  float c0 = fc[s * HDIM + i], s0 = fs[s * HDIM + i];
  float c1 = fc[s * HDIM + i + 32], s1 = fs[s * HDIM + i + 32];
  p[i] = x0 * c0 - x1 * s0;
  p[i + 32] = x1 * c1 + x0 * s1;
}

// ---------------- Flash attention (fp32), causal, GQA ----------------
// grid: (SEQ/16, BATCH*NHEADS). block: 256 (4 waves). Each wave owns 4 q rows.
__device__ inline float waveMax(float v) {
#pragma unroll
  for (int o = 32; o > 0; o >>= 1) v = fmaxf(v, __shfl_xor(v, o));
  return v;
}
__device__ inline float waveSum(float v) {
#pragma unroll
  for (int o = 32; o > 0; o >>= 1) v += __shfl_xor(v, o);
  return v;
}

__global__ __launch_bounds__(256) void attn_kernel(const float* __restrict__ Q,
                                                   const float* __restrict__ Kc,
                                                   const float* __restrict__ Vc,
                                                   float* __restrict__ O) {
  __shared__ float Ks[64][68];   // [key][dim], stride 68 floats (16B aligned rows)
  __shared__ float Vst[64][68];  // [dim][key] (transposed V tile)
  __shared__ float qs[16][64];   // [block q row][dim]
  __shared__ float ps[16][64];   // [block q row][key in tile]
  const int tid = threadIdx.x;
  const int lane = tid & 63;
  const int wid = tid >> 6;
  const int bh = blockIdx.y;           // 0..63
  const int b = bh >> 5;               // / NHEADS
  const int h = bh & 31;
  const int kh = h >> 2;               // n_rep = 4
  const int r0 = blockIdx.x * 16;
  const int rw = r0 + wid * 4;         // this wave's first q row

  float m[4], ssum[4], o[4];
#pragma unroll
  for (int j = 0; j < 4; j++) {
    float qv = Q[((size_t)(b * SEQ + rw + j) * NHEADS + h) * HDIM + lane] * 0.125f;
    qs[wid * 4 + j][lane] = qv;
    m[j] = -INFINITY;
    ssum[j] = 0.f;
    o[j] = 0.f;
  }

  const int kmax = r0 + 15;
  const int ntiles = (kmax >> 6) + 1;
  for (int t = 0; t < ntiles; t++) {
    const int k0 = t * 64;
    __syncthreads();  // previous tile's PV reads done (also covers qs writes @ t=0)
    // stage K tile [key][dim] and V tile transposed [dim][key]
    for (int e = tid; e < 64 * 64; e += 256) {
      int kr = e >> 6, kc = e & 63;
      size_t g = ((size_t)(b * SEQ + k0 + kr) * NKV + kh) * HDIM + kc;
      Ks[kr][kc] = Kc[g];
      Vst[kc][kr] = Vc[g];
    }
    __syncthreads();

    // scores: lane = key index within tile
    float acc[4] = {0.f, 0.f, 0.f, 0.f};
#pragma unroll
    for (int d4 = 0; d4 < 64; d4 += 4) {
      float4 k4 = *(float4*)&Ks[lane][d4];
#pragma unroll
      for (int j = 0; j < 4; j++) {
        float4 q4 = *(float4*)&qs[wid * 4 + j][d4];
        acc[j] += q4.x * k4.x + q4.y * k4.y + q4.z * k4.z + q4.w * k4.w;
      }
    }

    // online softmax per row; all waves execute (causality via nvalid clamp)
#pragma unroll
    for (int j = 0; j < 4; j++) {
      int nv = rw + j - k0 + 1;  // may be <=0 (tile beyond diagonal) or >64
      if (nv > 64) nv = 64;
      float sl = (lane < nv) ? acc[j] : -INFINITY;
      float tmax = waveMax(sl);
      float mnew = fmaxf(m[j], tmax);       // finite after tile 0; = m[j] if nv<=0
      float alpha = __expf(m[j] - mnew);    // 0 on first tile, 1 on empty tiles
      float p = (lane < nv) ? __expf(sl - mnew) : 0.f;
      float pssum = waveSum(p);
      ssum[j] = ssum[j] * alpha + pssum;
      m[j] = mnew;
      o[j] *= alpha;
      ps[wid * 4 + j][lane] = p;
    }
    __syncthreads();  // ps visible (uniform barrier: all waves run all tiles)

    // PV: lane = dim index
#pragma unroll
    for (int k4 = 0; k4 < 64; k4 += 4) {
      float4 v4 = *(float4*)&Vst[lane][k4];
#pragma unroll
      for (int j = 0; j < 4; j++) {
        float4 p4 = *(float4*)&ps[wid * 4 + j][k4];
        o[j] += p4.x * v4.x + p4.y * v4.y + p4.z * v4.z + p4.w * v4.w;
      }
    }
  }

#pragma unroll
  for (int j = 0; j < 4; j++) {
    float inv = 1.0f / ssum[j];
    O[((size_t)(b * SEQ + rw + j) * NHEADS + h) * HDIM + lane] = o[j] * inv;
  }
}

// ---------------- launch ----------------
extern "C" void kernel_launch(void* const* d_in, const int* in_sizes, int n_in,
                              void* d_out, int out_size, void* d_ws, size_t ws_size,
                              hipStream_t stream) {
  const float* x = (const float*)d_in[0];
  const float* fcos = (const float*)d_in[1];
  const float* fsin = (const float*)d_in[2];
  const float* wq = (const float*)d_in[3];
  const float* wk = (const float*)d_in[4];
  const float* wv = (const float*)d_in[5];
  const float* wo = (const float*)d_in[6];
  float* out = (float*)d_out;

  const int M = BATCH * SEQ;  // 4096
  float* ws = (float*)d_ws;
  float* Qb = ws;                                   // 4096*2048
  float* Kb = Qb + (size_t)M * EMBED;               // 4096*512
  float* Vb = Kb + (size_t)M * NKV * HDIM;          // 4096*512
  float* Ab = Vb + (size_t)M * NKV * HDIM;          // 4096*2048 (attn out)

  dim3 blk(256);
  // QKV projections
  gemm_nt<<<dim3(EMBED / BN, M / BM), blk, 0, stream>>>(x, wq, Qb, M, EMBED, EMBED);
  gemm_nt<<<dim3((NKV * HDIM) / BN, M / BM), blk, 0, stream>>>(x, wk, Kb, M, NKV * HDIM, EMBED);
  gemm_nt<<<dim3((NKV * HDIM) / BN, M / BM), blk, 0, stream>>>(x, wv, Vb, M, NKV * HDIM, EMBED);
  // RoPE on Q and K
  {
    int totQ = M * NHEADS * 32;
    rope_kernel<<<(totQ + 255) / 256, blk, 0, stream>>>(Qb, fcos, fsin, NHEADS, totQ);
    int totK = M * NKV * 32;
    rope_kernel<<<(totK + 255) / 256, blk, 0, stream>>>(Kb, fcos, fsin, NKV, totK);
  }
  // attention
  attn_kernel<<<dim3(SEQ / 16, BATCH * NHEADS), blk, 0, stream>>>(Qb, Kb, Vb, Ab);
  // output projection
  gemm_nt<<<dim3(EMBED / BN, M / BM), blk, 0, stream>>>(Ab, wo, out, M, EMBED, EMBED);
}

// Round 2
// 652.420 us; speedup vs baseline: 5.2882x; 5.2882x over previous
//
#include <hip/hip_runtime.h>

#define BATCH 2
#define SEQ 2048
#define EMBED 2048
#define NHEADS 32
#define NKV 8
#define HDIM 64

typedef __attribute__((ext_vector_type(8))) short short8;
typedef __attribute__((ext_vector_type(4))) float f32x4;

__device__ inline ushort f2bf(float f) {
  union { float f; unsigned u; } v{f};
  unsigned r = v.u + 0x7FFF + ((v.u >> 16) & 1);
  return (ushort)(r >> 16);
}
__device__ inline float bf2f(ushort u) {
  union { unsigned u; float f; } v{((unsigned)u) << 16};
  return v.f;
}

// ---------------- fp32 -> bf16 convert ----------------
__global__ void f32_to_bf16_kernel(const float* __restrict__ in,
                                   ushort* __restrict__ out, int n) {
  int i = (blockIdx.x * blockDim.x + threadIdx.x) * 4;
  if (i >= n) return;
  float4 v = *(const float4*)(in + i);
  ushort4 o;
  o.x = f2bf(v.x); o.y = f2bf(v.y); o.z = f2bf(v.z); o.w = f2bf(v.w);
  *(ushort4*)(out + i) = o;
}

// ---------------- bf16 MFMA GEMM: C[M,N] = A[M,K] * B[N,K]^T ----------------
// 128x128 tile, BK=32, 256 threads (4 waves, 2x2 of 64x64), 16 MFMA / K-step.
template <typename OutT>
__global__ __launch_bounds__(256) void gemm_bf16(const ushort* __restrict__ A,
                                                 const ushort* __restrict__ B,
                                                 OutT* __restrict__ C,
                                                 int M, int N, int K) {
  __shared__ ushort As[128][40];  // pad 32->40 (80B row, 16B aligned)
  __shared__ ushort Bs[128][40];
  const int tid = threadIdx.x;
  const int row = tid & 127, half = tid >> 7;  // staging: 16 bf16 per thread
  const int lane = tid & 63, wave = tid >> 6;
  const int quad = lane >> 4, l16 = lane & 15;
  const int m0 = blockIdx.y * 128, n0 = blockIdx.x * 128;
  const int wm = (wave >> 1) * 64, wn = (wave & 1) * 64;

  f32x4 acc[4][4] = {};
  for (int k0 = 0; k0 < K; k0 += 32) {
    const float4* pa = (const float4*)(A + (size_t)(m0 + row) * K + k0 + half * 16);
    float4 a0 = pa[0], a1 = pa[1];
    const float4* pb = (const float4*)(B + (size_t)(n0 + row) * K + k0 + half * 16);
    float4 b0 = pb[0], b1 = pb[1];
    __syncthreads();
    *(float4*)&As[row][half * 16] = a0;
    *(float4*)&As[row][half * 16 + 8] = a1;
    *(float4*)&Bs[row][half * 16] = b0;
    *(float4*)&Bs[row][half * 16 + 8] = b1;
    __syncthreads();
    short8 af[4], bf[4];
#pragma unroll
    for (int i = 0; i < 4; i++) af[i] = *(short8*)&As[wm + i * 16 + l16][quad * 8];
#pragma unroll
    for (int j = 0; j < 4; j++) bf[j] = *(short8*)&Bs[wn + j * 16 + l16][quad * 8];
#pragma unroll
    for (int i = 0; i < 4; i++)
#pragma unroll
      for (int j = 0; j < 4; j++)
        acc[i][j] = __builtin_amdgcn_mfma_f32_16x16x32_bf16(af[i], bf[j], acc[i][j], 0, 0, 0);
  }
#pragma unroll
  for (int i = 0; i < 4; i++) {
#pragma unroll
    for (int r = 0; r < 4; r++) {
      size_t rg = (size_t)(m0 + wm + i * 16 + quad * 4 + r);
#pragma unroll
      for (int j = 0; j < 4; j++) {
        float v = acc[i][j][r];
        int cg = n0 + wn + j * 16 + l16;
        if constexpr (sizeof(OutT) == 2)
          C[rg * N + cg] = f2bf(v);
        else
          C[rg * N + cg] = v;
      }
    }
  }
}

// ---------------- RoPE (bf16 in place), rotate_half convention ----------------
__global__ void rope_bf16(ushort* __restrict__ t, const float* __restrict__ fc,
                          const float* __restrict__ fs, int nHeads, int total) {
  int idx = blockIdx.x * blockDim.x + threadIdx.x;
  if (idx >= total) return;
  int i = idx & 31;
  int h = (idx >> 5) % nHeads;
  int tok = idx / (32 * nHeads);
  int s = tok & (SEQ - 1);
  ushort* p = t + ((size_t)tok * nHeads + h) * HDIM;
  float x0 = bf2f(p[i]), x1 = bf2f(p[i + 32]);
  float c0 = fc[s * HDIM + i], s0 = fs[s * HDIM + i];
  float c1 = fc[s * HDIM + i + 32], s1 = fs[s * HDIM + i + 32];
  p[i] = f2bf(x0 * c0 - x1 * s0);
  p[i + 32] = f2bf(x1 * c1 + x0 * s1);
}

// ---------------- MFMA flash attention (bf16 in, fp32 softmax) ----------------
// grid: (SEQ/64, BATCH*NHEADS), 256 threads. Wave w owns q rows qw..qw+15.
__global__ __launch_bounds__(256) void attn_mfma(const ushort* __restrict__ Q,
                                                 const ushort* __restrict__ Kc,
                                                 const ushort* __restrict__ Vc,
                                                 ushort* __restrict__ O) {
  __shared__ ushort Ks[64][72];      // [key][d], stride 144B
  __shared__ ushort Vt[64][72];      // [d][key] transposed
  __shared__ ushort Pw[4][16][72];   // per-wave P in A-layout [qrow][key]
  const int tid = threadIdx.x;
  const int lane = tid & 63, wave = tid >> 6;
  const int quad = lane >> 4, l16 = lane & 15;
  const int bh = blockIdx.y;
  const int b = bh >> 5, h = bh & 31, kh = h >> 2;
  const int q0 = blockIdx.x * 64;
  const int qw = q0 + wave * 16;

  // Q A-fragments in registers (reused across all key tiles)
  short8 qf[2];
#pragma unroll
  for (int c = 0; c < 2; c++)
    qf[c] = *(const short8*)(Q + (size_t)(b * SEQ + qw + l16) * EMBED + h * HDIM + c * 32 + quad * 8);

  float m[4], l[4];
  f32x4 o[4] = {};
#pragma unroll
  for (int r = 0; r < 4; r++) { m[r] = -INFINITY; l[r] = 0.f; }

  const int krow = tid & 63, kpart = tid >> 6;  // staging role
  const int ntiles = blockIdx.x + 1;
  for (int t = 0; t < ntiles; t++) {
    const int k0 = t * 64;
    __syncthreads();  // prior tile's K/V reads complete
    {
      size_t g = (size_t)(b * SEQ + k0 + krow) * (NKV * HDIM) + kh * HDIM + kpart * 16;
      const float4* kp = (const float4*)(Kc + g);
      float4 kv0 = kp[0], kv1 = kp[1];
      union { float4 f[2]; ushort u[16]; } vv;
      const float4* vp = (const float4*)(Vc + g);
      vv.f[0] = vp[0]; vv.f[1] = vp[1];
      *(float4*)&Ks[krow][kpart * 16] = kv0;
      *(float4*)&Ks[krow][kpart * 16 + 8] = kv1;
#pragma unroll
      for (int j = 0; j < 16; j++) Vt[kpart * 16 + j][krow] = vv.u[j];
    }
    __syncthreads();

    // S = Q K^T  (4 n-tiles of 16 keys)
    f32x4 s[4];
#pragma unroll
    for (int nt = 0; nt < 4; nt++) {
      short8 kf0 = *(short8*)&Ks[nt * 16 + l16][quad * 8];
      short8 kf1 = *(short8*)&Ks[nt * 16 + l16][32 + quad * 8];
      f32x4 z = {};
      z = __builtin_amdgcn_mfma_f32_16x16x32_bf16(qf[0], kf0, z, 0, 0, 0);
      s[nt] = __builtin_amdgcn_mfma_f32_16x16x32_bf16(qf[1], kf1, z, 0, 0, 0);
    }

    // online softmax per q row (row = quad*4 + r)
#pragma unroll
    for (int r = 0; r < 4; r++) {
      const int qi = qw + quad * 4 + r;
      float mx = -INFINITY;
#pragma unroll
      for (int nt = 0; nt < 4; nt++) {
        int kidx = k0 + nt * 16 + l16;
        float sv = (kidx <= qi) ? s[nt][r] * 0.125f : -INFINITY;
        s[nt][r] = sv;
        mx = fmaxf(mx, sv);
      }
#pragma unroll
      for (int off = 8; off > 0; off >>= 1) mx = fmaxf(mx, __shfl_xor(mx, off));
      float mnew = fmaxf(m[r], mx);          // finite from tile 0 on
      float al = __expf(m[r] - mnew);        // 0 on first tile, 1 on masked tiles
      float psum = 0.f;
#pragma unroll
      for (int nt = 0; nt < 4; nt++) {
        float p = __expf(s[nt][r] - mnew);   // masked -> exp(-inf)=0
        psum += p;
        Pw[wave][quad * 4 + r][nt * 16 + l16] = f2bf(p);
      }
#pragma unroll
      for (int off = 8; off > 0; off >>= 1) psum += __shfl_xor(psum, off);
      l[r] = l[r] * al + psum;
      m[r] = mnew;
#pragma unroll
      for (int dt = 0; dt < 4; dt++) o[dt][r] *= al;
    }
    __syncthreads();  // Pw visible (uniform barrier across waves)

    // O += P V  (4 d-tiles of 16)
    short8 pf0 = *(short8*)&Pw[wave][l16][quad * 8];
    short8 pf1 = *(short8*)&Pw[wave][l16][32 + quad * 8];
#pragma unroll
    for (int dt = 0; dt < 4; dt++) {
      short8 vf0 = *(short8*)&Vt[dt * 16 + l16][quad * 8];
      short8 vf1 = *(short8*)&Vt[dt * 16 + l16][32 + quad * 8];
      o[dt] = __builtin_amdgcn_mfma_f32_16x16x32_bf16(pf0, vf0, o[dt], 0, 0, 0);
      o[dt] = __builtin_amdgcn_mfma_f32_16x16x32_bf16(pf1, vf1, o[dt], 0, 0, 0);
    }
  }

#pragma unroll
  for (int r = 0; r < 4; r++) {
    float inv = 1.0f / l[r];
    size_t rowg = (size_t)(b * SEQ + qw + quad * 4 + r) * EMBED + h * HDIM;
#pragma unroll
    for (int dt = 0; dt < 4; dt++)
      O[rowg + dt * 16 + l16] = f2bf(o[dt][r] * inv);
  }
}

// ---------------- launch ----------------
extern "C" void kernel_launch(void* const* d_in, const int* in_sizes, int n_in,
                              void* d_out, int out_size, void* d_ws, size_t ws_size,
                              hipStream_t stream) {
  const float* x = (const float*)d_in[0];
  const float* fcos = (const float*)d_in[1];
  const float* fsin = (const float*)d_in[2];
  const float* wq = (const float*)d_in[3];
  const float* wk = (const float*)d_in[4];
  const float* wv = (const float*)d_in[5];
  const float* wo = (const float*)d_in[6];
  float* out = (float*)d_out;

  const int M = BATCH * SEQ;              // 4096
  const int NXK = NKV * HDIM;             // 512
  ushort* ws = (ushort*)d_ws;
  ushort* xb = ws;                        // M*EMBED
  ushort* wqb = xb + (size_t)M * EMBED;   // EMBED*EMBED
  ushort* wkb = wqb + (size_t)EMBED * EMBED;
  ushort* wvb = wkb + (size_t)NXK * EMBED;
  ushort* wob = wvb + (size_t)NXK * EMBED;
  ushort* Qb = wob + (size_t)EMBED * EMBED;
  ushort* Kb = Qb + (size_t)M * EMBED;
  ushort* Vb = Kb + (size_t)M * NXK;
  ushort* Ab = Vb + (size_t)M * NXK;      // attention out, bf16

  dim3 blk(256);
  auto cvt = [&](const float* src, ushort* dst, size_t n) {
    f32_to_bf16_kernel<<<(n / 4 + 255) / 256, blk, 0, stream>>>(src, dst, (int)n);
  };
  cvt(x, xb, (size_t)M * EMBED);
  cvt(wq, wqb, (size_t)EMBED * EMBED);
  cvt(wk, wkb, (size_t)NXK * EMBED);
  cvt(wv, wvb, (size_t)NXK * EMBED);
  cvt(wo, wob, (size_t)EMBED * EMBED);

  gemm_bf16<ushort><<<dim3(EMBED / 128, M / 128), blk, 0, stream>>>(xb, wqb, Qb, M, EMBED, EMBED);
  gemm_bf16<ushort><<<dim3(NXK / 128, M / 128), blk, 0, stream>>>(xb, wkb, Kb, M, NXK, EMBED);
  gemm_bf16<ushort><<<dim3(NXK / 128, M / 128), blk, 0, stream>>>(xb, wvb, Vb, M, NXK, EMBED);

  {
    int totQ = M * NHEADS * 32;
    rope_bf16<<<(totQ + 255) / 256, blk, 0, stream>>>(Qb, fcos, fsin, NHEADS, totQ);
    int totK = M * NKV * 32;
    rope_bf16<<<(totK + 255) / 256, blk, 0, stream>>>(Kb, fcos, fsin, NKV, totK);
  }

  attn_mfma<<<dim3(SEQ / 64, BATCH * NHEADS), blk, 0, stream>>>(Qb, Kb, Vb, Ab);

  gemm_bf16<float><<<dim3(EMBED / 128, M / 128), blk, 0, stream>>>(Ab, wob, out, M, EMBED, EMBED);
}

// Round 3
// 462.878 us; speedup vs baseline: 7.4537x; 1.4095x over previous
//
#include <hip/hip_runtime.h>

#define BATCH 2
#define SEQ 2048
#define EMBED 2048
#define NHEADS 32
#define NKV 8
#define HDIM 64
#define QKV_LD 3072  // fused [Q(2048) | K(512) | V(512)] row stride

typedef __attribute__((ext_vector_type(8))) short short8;
typedef __attribute__((ext_vector_type(4))) float f32x4;

__device__ inline ushort f2bf(float f) {
  union { float f; unsigned u; } v{f};
  unsigned r = v.u + 0x7FFF + ((v.u >> 16) & 1);
  return (ushort)(r >> 16);
}
__device__ inline float bf2f(ushort u) {
  union { unsigned u; float f; } v{((unsigned)u) << 16};
  return v.f;
}

__device__ inline void gload16(const ushort* g, ushort* l) {
  __builtin_amdgcn_global_load_lds(
      (const __attribute__((address_space(1))) unsigned*)g,
      (__attribute__((address_space(3))) unsigned*)l, 16, 0, 0);
}

// ---------------- fp32 -> bf16 convert ----------------
__global__ void f32_to_bf16_kernel(const float* __restrict__ in,
                                   ushort* __restrict__ out, int n) {
  int i = (blockIdx.x * blockDim.x + threadIdx.x) * 4;
  if (i >= n) return;
  float4 v = *(const float4*)(in + i);
  ushort4 o;
  o.x = f2bf(v.x); o.y = f2bf(v.y); o.z = f2bf(v.z); o.w = f2bf(v.w);
  *(ushort4*)(out + i) = o;
}

// ---------------- bf16 MFMA GEMM (m97 structure): C[M,N] = A * B^T ----------------
// 128x128 tile, BK=32, 4 waves 2x2, global_load_lds staging (unpadded LDS).
template <typename OutT>
__global__ __launch_bounds__(256) void gemm_bf16(const ushort* __restrict__ A,
                                                 const ushort* __restrict__ B,
                                                 OutT* __restrict__ C,
                                                 int M, int N, int K) {
  __shared__ ushort As[128][32];  // unpadded: global_load_lds lane order
  __shared__ ushort Bs[128][32];
  const int tid = threadIdx.x;
  const int lane = tid & 63, wave = tid >> 6;
  const int quad = lane >> 4, l16 = lane & 15;
  const int m0 = blockIdx.y * 128, n0 = blockIdx.x * 128;
  const int wm = (wave >> 1) * 64, wn = (wave & 1) * 64;
  const int srow = lane >> 2, skq = (lane & 3) * 8;  // staging lane roles

  f32x4 acc[4][4] = {};
  for (int k0 = 0; k0 < K; k0 += 32) {
    const ushort* ga = A + (size_t)(m0 + wave * 32 + srow) * K + k0 + skq;
    const ushort* gb = B + (size_t)(n0 + wave * 32 + srow) * K + k0 + skq;
    __syncthreads();  // prior frag reads done before overwrite
    gload16(ga, &As[wave * 32][0]);
    gload16(ga + (size_t)16 * K, &As[wave * 32 + 16][0]);
    gload16(gb, &Bs[wave * 32][0]);
    gload16(gb + (size_t)16 * K, &Bs[wave * 32 + 16][0]);
    __syncthreads();  // drains vmcnt (global_load_lds) + visibility
    short8 af[4], bf[4];
#pragma unroll
    for (int i = 0; i < 4; i++) af[i] = *(short8*)&As[wm + i * 16 + l16][quad * 8];
#pragma unroll
    for (int j = 0; j < 4; j++) bf[j] = *(short8*)&Bs[wn + j * 16 + l16][quad * 8];
#pragma unroll
    for (int i = 0; i < 4; i++)
#pragma unroll
      for (int j = 0; j < 4; j++)
        acc[i][j] = __builtin_amdgcn_mfma_f32_16x16x32_bf16(af[i], bf[j], acc[i][j], 0, 0, 0);
  }
#pragma unroll
  for (int i = 0; i < 4; i++) {
#pragma unroll
    for (int r = 0; r < 4; r++) {
      size_t rg = (size_t)(m0 + wm + i * 16 + quad * 4 + r);
#pragma unroll
      for (int j = 0; j < 4; j++) {
        float v = acc[i][j][r];
        int cg = n0 + wn + j * 16 + l16;
        if constexpr (sizeof(OutT) == 2)
          C[rg * N + cg] = f2bf(v);
        else
          C[rg * N + cg] = v;
      }
    }
  }
}

// ---------------- RoPE on fused QKV (heads 0..39 = Q then K), prescale Q ----------------
__global__ void rope_qk(ushort* __restrict__ t, const float* __restrict__ fc,
                        const float* __restrict__ fs, int total) {
  int idx = blockIdx.x * blockDim.x + threadIdx.x;
  if (idx >= total) return;
  int i = idx & 31;
  int hh = (idx >> 5) % 40;           // 0..31 Q heads, 32..39 K heads (cols contiguous)
  int tok = idx / (32 * 40);
  int s = tok & (SEQ - 1);
  float scale = (hh < 32) ? 0.125f : 1.0f;  // fold 1/sqrt(64) into Q (exact in bf16)
  ushort* p = t + (size_t)tok * QKV_LD + hh * 64;
  float x0 = bf2f(p[i]), x1 = bf2f(p[i + 32]);
  float c0 = fc[s * HDIM + i], s0 = fs[s * HDIM + i];
  float c1 = fc[s * HDIM + i + 32], s1 = fs[s * HDIM + i + 32];
  p[i] = f2bf((x0 * c0 - x1 * s0) * scale);
  p[i + 32] = f2bf((x1 * c1 + x0 * s1) * scale);
}

// ---------------- MFMA flash attention ----------------
// grid: (SEQ/128, BATCH*NHEADS), 256 thr. Block owns 128 q rows (2 subtiles of 64);
// wave w owns rows w*16..w*16+15 of each subtile. Heavy blocks launched first.
__global__ __launch_bounds__(256) void attn_mfma(const ushort* __restrict__ QKV,
                                                 ushort* __restrict__ O) {
  __shared__ ushort Ks[64][72];
  __shared__ ushort Vt[64][72];
  __shared__ ushort Pw[4][16][72];
  const int tid = threadIdx.x;
  const int lane = tid & 63, wave = tid >> 6;
  const int quad = lane >> 4, l16 = lane & 15;
  const int bh = blockIdx.y;
  const int b = bh >> 5, h = bh & 31, kh = h >> 2;
  const int bx = gridDim.x - 1 - blockIdx.x;  // heavy (long) blocks first
  const int q0 = bx * 128;

  short8 qf[2][2];
#pragma unroll
  for (int u = 0; u < 2; u++)
#pragma unroll
    for (int c = 0; c < 2; c++)
      qf[u][c] = *(const short8*)(QKV +
          (size_t)(b * SEQ + q0 + u * 64 + wave * 16 + l16) * QKV_LD +
          h * HDIM + c * 32 + quad * 8);

  short8 ones8;
#pragma unroll
  for (int i = 0; i < 8; i++) ones8[i] = (short)0x3F80;  // bf16 1.0

  f32x4 o[2][5] = {};  // [subtile][4 d-tiles + rowsum]
  float m[2][4];
#pragma unroll
  for (int u = 0; u < 2; u++)
#pragma unroll
    for (int r = 0; r < 4; r++) m[u][r] = -INFINITY;

  const ushort* Kbase = QKV + (size_t)b * SEQ * QKV_LD + 2048 + kh * HDIM;
  const ushort* Vbase = Kbase + 512;
  const int ntiles = 2 * bx + 2;

  for (int t = 0; t < ntiles; t++) {
    const int k0 = t * 64;
    __syncthreads();  // all waves done with prior Ks/Vt
    {
      size_t g = (size_t)(k0 + lane) * QKV_LD + wave * 16;
      const float4* kp = (const float4*)(Kbase + g);
      float4 kv0 = kp[0], kv1 = kp[1];
      union { float4 f[2]; ushort u[16]; } vv;
      const float4* vp = (const float4*)(Vbase + g);
      vv.f[0] = vp[0]; vv.f[1] = vp[1];
      *(float4*)&Ks[lane][wave * 16] = kv0;
      *(float4*)&Ks[lane][wave * 16 + 8] = kv1;
#pragma unroll
      for (int j = 0; j < 16; j++) Vt[wave * 16 + j][lane] = vv.u[j];
    }
    __syncthreads();

#pragma unroll
    for (int u = 0; u < 2; u++) {
      const int diag = 2 * bx + u;
      if (t > diag) continue;  // wave-uniform

      f32x4 s[4];
#pragma unroll
      for (int nt = 0; nt < 4; nt++) {
        short8 kf0 = *(short8*)&Ks[nt * 16 + l16][quad * 8];
        short8 kf1 = *(short8*)&Ks[nt * 16 + l16][32 + quad * 8];
        f32x4 z = {};
        z = __builtin_amdgcn_mfma_f32_16x16x32_bf16(qf[u][0], kf0, z, 0, 0, 0);
        s[nt] = __builtin_amdgcn_mfma_f32_16x16x32_bf16(qf[u][1], kf1, z, 0, 0, 0);
      }

      if (t == diag) {  // diagonal tile: masked softmax
#pragma unroll
        for (int r = 0; r < 4; r++) {
          const int rloc = wave * 16 + quad * 4 + r;  // row offset rel. to k0
          float mx = -INFINITY;
#pragma unroll
          for (int nt = 0; nt < 4; nt++) {
            float sv = (nt * 16 + l16 <= rloc) ? s[nt][r] : -INFINITY;
            s[nt][r] = sv;
            mx = fmaxf(mx, sv);
          }
#pragma unroll
          for (int off = 8; off > 0; off >>= 1) mx = fmaxf(mx, __shfl_xor(mx, off));
          float mnew = fmaxf(m[u][r], mx);
          float al = __expf(m[u][r] - mnew);
#pragma unroll
          for (int nt = 0; nt < 4; nt++)
            Pw[wave][quad * 4 + r][nt * 16 + l16] = f2bf(__expf(s[nt][r] - mnew));
          m[u][r] = mnew;
#pragma unroll
          for (int dt = 0; dt < 5; dt++) o[u][dt][r] *= al;
        }
      } else {  // full tile: no masking
#pragma unroll
        for (int r = 0; r < 4; r++) {
          float mx = fmaxf(fmaxf(s[0][r], s[1][r]), fmaxf(s[2][r], s[3][r]));
#pragma unroll
          for (int off = 8; off > 0; off >>= 1) mx = fmaxf(mx, __shfl_xor(mx, off));
          float mnew = fmaxf(m[u][r], mx);
          float al = __expf(m[u][r] - mnew);
#pragma unroll
          for (int nt = 0; nt < 4; nt++)
            Pw[wave][quad * 4 + r][nt * 16 + l16] = f2bf(__expf(s[nt][r] - mnew));
          m[u][r] = mnew;
#pragma unroll
          for (int dt = 0; dt < 5; dt++) o[u][dt][r] *= al;
        }
      }
      // PV + ones-column rowsum. Pw is per-wave: no barrier needed (lgkmcnt only).
      short8 pf0 = *(short8*)&Pw[wave][l16][quad * 8];
      short8 pf1 = *(short8*)&Pw[wave][l16][32 + quad * 8];
#pragma unroll
      for (int dt = 0; dt < 4; dt++) {
        short8 vf0 = *(short8*)&Vt[dt * 16 + l16][quad * 8];
        short8 vf1 = *(short8*)&Vt[dt * 16 + l16][32 + quad * 8];
        o[u][dt] = __builtin_amdgcn_mfma_f32_16x16x32_bf16(pf0, vf0, o[u][dt], 0, 0, 0);
        o[u][dt] = __builtin_amdgcn_mfma_f32_16x16x32_bf16(pf1, vf1, o[u][dt], 0, 0, 0);
      }
      o[u][4] = __builtin_amdgcn_mfma_f32_16x16x32_bf16(pf0, ones8, o[u][4], 0, 0, 0);
      o[u][4] = __builtin_amdgcn_mfma_f32_16x16x32_bf16(pf1, ones8, o[u][4], 0, 0, 0);
    }
  }

#pragma unroll
  for (int u = 0; u < 2; u++)
#pragma unroll
    for (int r = 0; r < 4; r++) {
      float inv = 1.0f / o[u][4][r];  // every lane's col holds the rowsum
      size_t rowg = (size_t)(b * SEQ + q0 + u * 64 + wave * 16 + quad * 4 + r) * EMBED + h * HDIM;
#pragma unroll
      for (int dt = 0; dt < 4; dt++)
        O[rowg + dt * 16 + l16] = f2bf(o[u][dt][r] * inv);
    }
}

// ---------------- launch ----------------
extern "C" void kernel_launch(void* const* d_in, const int* in_sizes, int n_in,
                              void* d_out, int out_size, void* d_ws, size_t ws_size,
                              hipStream_t stream) {
  const float* x = (const float*)d_in[0];
  const float* fcos = (const float*)d_in[1];
  const float* fsin = (const float*)d_in[2];
  const float* wq = (const float*)d_in[3];
  const float* wk = (const float*)d_in[4];
  const float* wv = (const float*)d_in[5];
  const float* wo = (const float*)d_in[6];
  float* out = (float*)d_out;

  const int M = BATCH * SEQ;  // 4096
  ushort* ws = (ushort*)d_ws;
  ushort* xb = ws;                                   // M*2048
  ushort* wqkv = xb + (size_t)M * EMBED;             // 3072*2048 (wq|wk|wv rows)
  ushort* wob = wqkv + (size_t)QKV_LD * EMBED;       // 2048*2048
  ushort* QKVb = wob + (size_t)EMBED * EMBED;        // M*3072
  ushort* Ab = QKVb + (size_t)M * QKV_LD;            // M*2048

  dim3 blk(256);
  auto cvt = [&](const float* src, ushort* dst, size_t n) {
    f32_to_bf16_kernel<<<(n / 4 + 255) / 256, blk, 0, stream>>>(src, dst, (int)n);
  };
  cvt(x, xb, (size_t)M * EMBED);
  cvt(wq, wqkv, (size_t)EMBED * EMBED);
  cvt(wk, wqkv + (size_t)EMBED * EMBED, (size_t)512 * EMBED);
  cvt(wv, wqkv + (size_t)(EMBED + 512) * EMBED, (size_t)512 * EMBED);
  cvt(wo, wob, (size_t)EMBED * EMBED);

  // fused QKV projection: C[M,3072] = x * [wq|wk|wv]^T
  gemm_bf16<ushort><<<dim3(QKV_LD / 128, M / 128), blk, 0, stream>>>(xb, wqkv, QKVb, M, QKV_LD, EMBED);

  // RoPE on Q+K region (40 contiguous 64-col heads), Q prescaled by 0.125
  {
    int tot = M * 40 * 32;
    rope_qk<<<(tot + 255) / 256, blk, 0, stream>>>(QKVb, fcos, fsin, tot);
  }

  attn_mfma<<<dim3(SEQ / 128, BATCH * NHEADS), blk, 0, stream>>>(QKVb, Ab);

  gemm_bf16<float><<<dim3(EMBED / 128, M / 128), blk, 0, stream>>>(Ab, wob, out, M, EMBED, EMBED);
}

// Round 4
// 344.974 us; speedup vs baseline: 10.0012x; 1.3418x over previous
//
#include <hip/hip_runtime.h>

#define BATCH 2
#define SEQ 2048
#define EMBED 2048
#define NHEADS 32
#define NKV 8
#define HDIM 64
#define QKV_LD 3072  // fused [Q(2048) | K(512) | V(512)] row stride

typedef __attribute__((ext_vector_type(8))) short short8;
typedef __attribute__((ext_vector_type(4))) float f32x4;

__device__ inline ushort f2bf(float f) {
  union { float f; unsigned u; } v{f};
  unsigned r = v.u + 0x7FFF + ((v.u >> 16) & 1);
  return (ushort)(r >> 16);
}
__device__ inline float bf2f(ushort u) {
  union { unsigned u; float f; } v{((unsigned)u) << 16};
  return v.f;
}
__device__ inline unsigned fbits(float f) {
  union { float f; unsigned u; } v{f};
  return v.u;
}

__device__ inline void gload16(const ushort* g, ushort* l) {
  __builtin_amdgcn_global_load_lds(
      (const __attribute__((address_space(1))) unsigned*)g,
      (__attribute__((address_space(3))) unsigned*)l, 16, 0, 0);
}

// ---------------- fp32 -> bf16 convert ----------------
__global__ void f32_to_bf16_kernel(const float* __restrict__ in,
                                   ushort* __restrict__ out, int n) {
  int i = (blockIdx.x * blockDim.x + threadIdx.x) * 4;
  if (i >= n) return;
  float4 v = *(const float4*)(in + i);
  ushort4 o;
  o.x = f2bf(v.x); o.y = f2bf(v.y); o.z = f2bf(v.z); o.w = f2bf(v.w);
  *(ushort4*)(out + i) = o;
}

// ---------------- bf16 MFMA GEMM (m97 structure): C[M,N] = A * B^T ----------------
template <typename OutT>
__global__ __launch_bounds__(256) void gemm_bf16(const ushort* __restrict__ A,
                                                 const ushort* __restrict__ B,
                                                 OutT* __restrict__ C,
                                                 int M, int N, int K) {
  __shared__ ushort As[128][32];
  __shared__ ushort Bs[128][32];
  const int tid = threadIdx.x;
  const int lane = tid & 63, wave = tid >> 6;
  const int quad = lane >> 4, l16 = lane & 15;
  const int m0 = blockIdx.y * 128, n0 = blockIdx.x * 128;
  const int wm = (wave >> 1) * 64, wn = (wave & 1) * 64;
  const int srow = lane >> 2, skq = (lane & 3) * 8;

  f32x4 acc[4][4] = {};
  for (int k0 = 0; k0 < K; k0 += 32) {
    const ushort* ga = A + (size_t)(m0 + wave * 32 + srow) * K + k0 + skq;
    const ushort* gb = B + (size_t)(n0 + wave * 32 + srow) * K + k0 + skq;
    __syncthreads();
    gload16(ga, &As[wave * 32][0]);
    gload16(ga + (size_t)16 * K, &As[wave * 32 + 16][0]);
    gload16(gb, &Bs[wave * 32][0]);
    gload16(gb + (size_t)16 * K, &Bs[wave * 32 + 16][0]);
    __syncthreads();
    short8 af[4], bf[4];
#pragma unroll
    for (int i = 0; i < 4; i++) af[i] = *(short8*)&As[wm + i * 16 + l16][quad * 8];
#pragma unroll
    for (int j = 0; j < 4; j++) bf[j] = *(short8*)&Bs[wn + j * 16 + l16][quad * 8];
#pragma unroll
    for (int i = 0; i < 4; i++)
#pragma unroll
      for (int j = 0; j < 4; j++)
        acc[i][j] = __builtin_amdgcn_mfma_f32_16x16x32_bf16(af[i], bf[j], acc[i][j], 0, 0, 0);
  }
#pragma unroll
  for (int i = 0; i < 4; i++) {
#pragma unroll
    for (int r = 0; r < 4; r++) {
      size_t rg = (size_t)(m0 + wm + i * 16 + quad * 4 + r);
#pragma unroll
      for (int j = 0; j < 4; j++) {
        float v = acc[i][j][r];
        int cg = n0 + wn + j * 16 + l16;
        if constexpr (sizeof(OutT) == 2)
          C[rg * N + cg] = f2bf(v);
        else
          C[rg * N + cg] = v;
      }
    }
  }
}

// ---------------- RoPE on fused QKV, Q prescaled by 1/sqrt(d) ----------------
__global__ void rope_qk(ushort* __restrict__ t, const float* __restrict__ fc,
                        const float* __restrict__ fs, int total) {
  int idx = blockIdx.x * blockDim.x + threadIdx.x;
  if (idx >= total) return;
  int i = idx & 31;
  int hh = (idx >> 5) % 40;  // 0..31 Q heads, 32..39 K heads
  int tok = idx / (32 * 40);
  int s = tok & (SEQ - 1);
  float scale = (hh < 32) ? 0.125f : 1.0f;
  ushort* p = t + (size_t)tok * QKV_LD + hh * 64;
  float x0 = bf2f(p[i]), x1 = bf2f(p[i + 32]);
  float c0 = fc[s * HDIM + i], s0 = fs[s * HDIM + i];
  float c1 = fc[s * HDIM + i + 32], s1 = fs[s * HDIM + i + 32];
  p[i] = f2bf((x0 * c0 - x1 * s0) * scale);
  p[i + 32] = f2bf((x1 * c1 + x0 * s1) * scale);
}

// ---------------- MFMA flash attention, transposed-S formulation ----------------
// Block p (0..15) owns q-tiles {p, 31-p} (64 rows each): constant ~33 tile-units.
// Wave w handles q rows (tile*64 + w*16 .. +15). S^T = K Q^T so each lane's
// 16 scores all belong to q = l16: in-lane max/sum + 2 shuffles only.
__global__ __launch_bounds__(256) void attn_mfma(const ushort* __restrict__ QKV,
                                                 ushort* __restrict__ O) {
  __shared__ ushort Ks[64][72];     // [key][d]
  __shared__ ushort Vt[64][72];     // [d][key]
  __shared__ ushort Pw[4][16][72];  // per-wave P[q][key]
  const int tid = threadIdx.x;
  const int lane = tid & 63, wave = tid >> 6;
  const int quad = lane >> 4, l16 = lane & 15;
  const int bh = blockIdx.y;
  const int b = bh >> 5, h = bh & 31, kh = h >> 2;
  const int p = blockIdx.x;
  const int qt[2] = {p, 31 - p};
  const int ntiles = 32 - p;

  // Q B-fragments (row = q, k = dim), resident all tiles
  short8 qf[2][2];
#pragma unroll
  for (int u = 0; u < 2; u++)
#pragma unroll
    for (int c = 0; c < 2; c++)
      qf[u][c] = *(const short8*)(QKV +
          (size_t)(b * SEQ + qt[u] * 64 + wave * 16 + l16) * QKV_LD +
          h * HDIM + c * 32 + quad * 8);

  f32x4 o[2][4] = {};  // O^T: lane l16=q, reg (dt, quad*4+r)=d
  float m[2] = {-INFINITY, -INFINITY}, l[2] = {0.f, 0.f};

  const ushort* Kbase = QKV + (size_t)b * SEQ * QKV_LD + 2048 + kh * HDIM;
  const ushort* Vbase = Kbase + 512;
  const int kp = tid & 31, dg = tid >> 5;  // V staging role
  const int relrow = wave * 16 + l16;      // q row rel. to diagonal tile base

  for (int t = 0; t < ntiles; t++) {
    const int k0 = t * 64;
    __syncthreads();  // all waves done with prior Ks/Vt
    {
      // K tile: [key][d], lane = key, wave = 16-col slab
      const float4* kpp = (const float4*)(Kbase + (size_t)(k0 + lane) * QKV_LD + wave * 16);
      float4 kv0 = kpp[0], kv1 = kpp[1];
      // V tile transposed with key-pair packing: thread = (keypair, 8-d group)
      const uint4* va4 = (const uint4*)(Vbase + (size_t)(k0 + 2 * kp) * QKV_LD + dg * 8);
      const uint4* vb4 = (const uint4*)(Vbase + (size_t)(k0 + 2 * kp + 1) * QKV_LD + dg * 8);
      uint4 va = va4[0], vb = vb4[0];
      *(float4*)&Ks[lane][wave * 16] = kv0;
      *(float4*)&Ks[lane][wave * 16 + 8] = kv1;
      const unsigned* vaw = (const unsigned*)&va;
      const unsigned* vbw = (const unsigned*)&vb;
#pragma unroll
      for (int j = 0; j < 8; j++) {
        unsigned pk = (j & 1)
            ? __builtin_amdgcn_perm(vbw[j >> 1], vaw[j >> 1], 0x07060302)   // hi halves
            : __builtin_amdgcn_perm(vbw[j >> 1], vaw[j >> 1], 0x05040100);  // lo halves
        *(unsigned*)&Vt[dg * 8 + j][2 * kp] = pk;
      }
    }
    __syncthreads();

#pragma unroll
    for (int u = 0; u < 2; u++) {
      const int diag = qt[u];
      if (t > diag) continue;  // wave-uniform

      // S^T tile: A = K rows (m=key), B = Q rows (n=q)
      f32x4 s[4];
#pragma unroll
      for (int nt = 0; nt < 4; nt++) {
        short8 kf0 = *(short8*)&Ks[nt * 16 + l16][quad * 8];
        short8 kf1 = *(short8*)&Ks[nt * 16 + l16][32 + quad * 8];
        f32x4 z = {};
        z = __builtin_amdgcn_mfma_f32_16x16x32_bf16(kf0, qf[u][0], z, 0, 0, 0);
        s[nt] = __builtin_amdgcn_mfma_f32_16x16x32_bf16(kf1, qf[u][1], z, 0, 0, 0);
      }

      if (t == diag) {  // mask keys > q (key_rel = nt*16+quad*4+r, q_rel = relrow)
#pragma unroll
        for (int nt = 0; nt < 4; nt++)
#pragma unroll
          for (int r = 0; r < 4; r++)
            if (nt * 16 + quad * 4 + r > relrow) s[nt][r] = -INFINITY;
      }

      // in-lane row max (all 16 scores belong to q=l16) + 2 shuffles
      float mx = -INFINITY;
#pragma unroll
      for (int nt = 0; nt < 4; nt++)
#pragma unroll
        for (int r = 0; r < 4; r++) mx = fmaxf(mx, s[nt][r]);
      mx = fmaxf(mx, __shfl_xor(mx, 16));
      mx = fmaxf(mx, __shfl_xor(mx, 32));
      float mnew = fmaxf(m[u], mx);
      float al = __expf(m[u] - mnew);
      m[u] = mnew;

      float pv[16];
      float psum = 0.f;
#pragma unroll
      for (int nt = 0; nt < 4; nt++)
#pragma unroll
        for (int r = 0; r < 4; r++) {
          float pe = __expf(s[nt][r] - mnew);
          pv[nt * 4 + r] = pe;
          psum += pe;
        }
      psum += __shfl_xor(psum, 16);
      psum += __shfl_xor(psum, 32);
      l[u] = l[u] * al + psum;
#pragma unroll
      for (int dt = 0; dt < 4; dt++)
#pragma unroll
        for (int r = 0; r < 4; r++) o[u][dt][r] *= al;

      // P[q][key] store: pairs are column-adjacent -> v_perm truncate-pack, b64
#pragma unroll
      for (int nt = 0; nt < 4; nt++) {
        unsigned lo = __builtin_amdgcn_perm(fbits(pv[nt * 4 + 1]), fbits(pv[nt * 4 + 0]), 0x07060302);
        unsigned hi = __builtin_amdgcn_perm(fbits(pv[nt * 4 + 3]), fbits(pv[nt * 4 + 2]), 0x07060302);
        uint2 pk; pk.x = lo; pk.y = hi;
        *(uint2*)&Pw[wave][l16][nt * 16 + quad * 4] = pk;
      }
      // per-wave LDS: same-wave write->read, no block barrier needed
      short8 pf0 = *(short8*)&Pw[wave][l16][quad * 8];
      short8 pf1 = *(short8*)&Pw[wave][l16][32 + quad * 8];
#pragma unroll
      for (int dt = 0; dt < 4; dt++) {
        short8 vf0 = *(short8*)&Vt[dt * 16 + l16][quad * 8];
        short8 vf1 = *(short8*)&Vt[dt * 16 + l16][32 + quad * 8];
        o[u][dt] = __builtin_amdgcn_mfma_f32_16x16x32_bf16(vf0, pf0, o[u][dt], 0, 0, 0);
        o[u][dt] = __builtin_amdgcn_mfma_f32_16x16x32_bf16(vf1, pf1, o[u][dt], 0, 0, 0);
      }
    }
  }

  // epilogue: lane l16=q holds O[q][dt*16+quad*4+r] -> packed 8B stores
#pragma unroll
  for (int u = 0; u < 2; u++) {
    float inv = 1.0f / l[u];
    size_t rowg = (size_t)(b * SEQ + qt[u] * 64 + wave * 16 + l16) * EMBED + h * HDIM;
#pragma unroll
    for (int dt = 0; dt < 4; dt++) {
      ushort q0 = f2bf(o[u][dt][0] * inv), q1 = f2bf(o[u][dt][1] * inv);
      ushort q2 = f2bf(o[u][dt][2] * inv), q3 = f2bf(o[u][dt][3] * inv);
      uint2 pk;
      pk.x = (unsigned)q0 | ((unsigned)q1 << 16);
      pk.y = (unsigned)q2 | ((unsigned)q3 << 16);
      *(uint2*)&O[rowg + dt * 16 + quad * 4] = pk;
    }
  }
}

// ---------------- launch ----------------
extern "C" void kernel_launch(void* const* d_in, const int* in_sizes, int n_in,
                              void* d_out, int out_size, void* d_ws, size_t ws_size,
                              hipStream_t stream) {
  const float* x = (const float*)d_in[0];
  const float* fcos = (const float*)d_in[1];
  const float* fsin = (const float*)d_in[2];
  const float* wq = (const float*)d_in[3];
  const float* wk = (const float*)d_in[4];
  const float* wv = (const float*)d_in[5];
  const float* wo = (const float*)d_in[6];
  float* out = (float*)d_out;

  const int M = BATCH * SEQ;  // 4096
  ushort* ws = (ushort*)d_ws;
  ushort* xb = ws;
  ushort* wqkv = xb + (size_t)M * EMBED;
  ushort* wob = wqkv + (size_t)QKV_LD * EMBED;
  ushort* QKVb = wob + (size_t)EMBED * EMBED;
  ushort* Ab = QKVb + (size_t)M * QKV_LD;

  dim3 blk(256);
  auto cvt = [&](const float* src, ushort* dst, size_t n) {
    f32_to_bf16_kernel<<<(n / 4 + 255) / 256, blk, 0, stream>>>(src, dst, (int)n);
  };
  cvt(x, xb, (size_t)M * EMBED);
  cvt(wq, wqkv, (size_t)EMBED * EMBED);
  cvt(wk, wqkv + (size_t)EMBED * EMBED, (size_t)512 * EMBED);
  cvt(wv, wqkv + (size_t)(EMBED + 512) * EMBED, (size_t)512 * EMBED);
  cvt(wo, wob, (size_t)EMBED * EMBED);

  gemm_bf16<ushort><<<dim3(QKV_LD / 128, M / 128), blk, 0, stream>>>(xb, wqkv, QKVb, M, QKV_LD, EMBED);

  {
    int tot = M * 40 * 32;
    rope_qk<<<(tot + 255) / 256, blk, 0, stream>>>(QKVb, fcos, fsin, tot);
  }

  attn_mfma<<<dim3(16, BATCH * NHEADS), blk, 0, stream>>>(QKVb, Ab);

  gemm_bf16<float><<<dim3(EMBED / 128, M / 128), blk, 0, stream>>>(Ab, wob, out, M, EMBED, EMBED);
}

// Round 6
// 328.228 us; speedup vs baseline: 10.5114x; 1.0510x over previous
//
#include <hip/hip_runtime.h>

#define BATCH 2
#define SEQ 2048
#define EMBED 2048
#define NHEADS 32
#define NKV 8
#define HDIM 64
#define QKV_LD 3072  // fused [Q(2048) | K(512) | V(512)] row stride
#define LOG2E 1.44269504088896f

typedef __attribute__((ext_vector_type(8))) short short8;
typedef __attribute__((ext_vector_type(4))) float f32x4;

__device__ inline float hw_exp2(float x) { return __builtin_amdgcn_exp2f(x); }

__device__ inline ushort f2bf(float f) {
  union { float f; unsigned u; } v{f};
  unsigned r = v.u + 0x7FFF + ((v.u >> 16) & 1);
  return (ushort)(r >> 16);
}
__device__ inline float bf2f(ushort u) {
  union { unsigned u; float f; } v{((unsigned)u) << 16};
  return v.f;
}
__device__ inline unsigned fbits(float f) {
  union { float f; unsigned u; } v{f};
  return v.u;
}

__device__ inline void gload16(const ushort* g, ushort* l) {
  __builtin_amdgcn_global_load_lds(
      (const __attribute__((address_space(1))) unsigned*)g,
      (__attribute__((address_space(3))) unsigned*)l, 16, 0, 0);
}

// ---------------- fused fp32 -> bf16 convert (all 5 tensors, 1 launch) ----------------
// element ranges: x[0,8388608) wq[..12582912) wk[..13631488) wv[..14680064) wo[..18874368)
__global__ __launch_bounds__(256) void cvt_all(const float* __restrict__ x,
                                               const float* __restrict__ wq,
                                               const float* __restrict__ wk,
                                               const float* __restrict__ wv,
                                               const float* __restrict__ wo,
                                               ushort* __restrict__ xb,
                                               ushort* __restrict__ wqkv,
                                               ushort* __restrict__ wob) {
  size_t e = (size_t)(blockIdx.x * blockDim.x + threadIdx.x) * 8;
  const float* src;
  ushort* dst;
  if (e < 8388608u) { src = x + e; dst = xb + e; }
  else if (e < 12582912u) { size_t o = e - 8388608u; src = wq + o; dst = wqkv + o; }
  else if (e < 13631488u) { size_t o = e - 12582912u; src = wk + o; dst = wqkv + 4194304u + o; }
  else if (e < 14680064u) { size_t o = e - 13631488u; src = wv + o; dst = wqkv + 5242880u + o; }
  else { size_t o = e - 14680064u; src = wo + o; dst = wob + o; }
  float4 v0 = ((const float4*)src)[0];
  float4 v1 = ((const float4*)src)[1];
  union { uint4 v; ushort u[8]; } pk;
  pk.u[0] = f2bf(v0.x); pk.u[1] = f2bf(v0.y); pk.u[2] = f2bf(v0.z); pk.u[3] = f2bf(v0.w);
  pk.u[4] = f2bf(v1.x); pk.u[5] = f2bf(v1.y); pk.u[6] = f2bf(v1.z); pk.u[7] = f2bf(v1.w);
  *(uint4*)dst = pk.v;
}

// ---------------- bf16 MFMA GEMM (m97 structure): C[M,N] = A * B^T ----------------
template <typename OutT>
__global__ __launch_bounds__(256) void gemm_bf16(const ushort* __restrict__ A,
                                                 const ushort* __restrict__ B,
                                                 OutT* __restrict__ C,
                                                 int M, int N, int K) {
  __shared__ ushort As[128][32];
  __shared__ ushort Bs[128][32];
  const int tid = threadIdx.x;
  const int lane = tid & 63, wave = tid >> 6;
  const int quad = lane >> 4, l16 = lane & 15;
  const int m0 = blockIdx.y * 128, n0 = blockIdx.x * 128;
  const int wm = (wave >> 1) * 64, wn = (wave & 1) * 64;
  const int srow = lane >> 2, skq = (lane & 3) * 8;

  f32x4 acc[4][4] = {};
  for (int k0 = 0; k0 < K; k0 += 32) {
    const ushort* ga = A + (size_t)(m0 + wave * 32 + srow) * K + k0 + skq;
    const ushort* gb = B + (size_t)(n0 + wave * 32 + srow) * K + k0 + skq;
    __syncthreads();
    gload16(ga, &As[wave * 32][0]);
    gload16(ga + (size_t)16 * K, &As[wave * 32 + 16][0]);
    gload16(gb, &Bs[wave * 32][0]);
    gload16(gb + (size_t)16 * K, &Bs[wave * 32 + 16][0]);
    __syncthreads();
    short8 af[4], bf[4];
#pragma unroll
    for (int i = 0; i < 4; i++) af[i] = *(short8*)&As[wm + i * 16 + l16][quad * 8];
#pragma unroll
    for (int j = 0; j < 4; j++) bf[j] = *(short8*)&Bs[wn + j * 16 + l16][quad * 8];
#pragma unroll
    for (int i = 0; i < 4; i++)
#pragma unroll
      for (int j = 0; j < 4; j++)
        acc[i][j] = __builtin_amdgcn_mfma_f32_16x16x32_bf16(af[i], bf[j], acc[i][j], 0, 0, 0);
  }
#pragma unroll
  for (int i = 0; i < 4; i++) {
#pragma unroll
    for (int r = 0; r < 4; r++) {
      size_t rg = (size_t)(m0 + wm + i * 16 + quad * 4 + r);
#pragma unroll
      for (int j = 0; j < 4; j++) {
        float v = acc[i][j][r];
        int cg = n0 + wn + j * 16 + l16;
        if constexpr (sizeof(OutT) == 2)
          C[rg * N + cg] = f2bf(v);
        else
          C[rg * N + cg] = v;
      }
    }
  }
}

// ---------------- vectorized RoPE on fused QKV ----------------
// Q heads prescaled by 0.125*log2(e) (exp2-domain softmax downstream).
// thread = (tok, hh<40, g<4): handles dims [g*8, g*8+8) and [g*8+32, g*8+40).
__global__ __launch_bounds__(256) void rope_qk(ushort* __restrict__ t,
                                               const float* __restrict__ fc,
                                               const float* __restrict__ fs,
                                               int total) {
  int idx = blockIdx.x * blockDim.x + threadIdx.x;
  if (idx >= total) return;
  int g = idx & 3;
  int hh = (idx >> 2) % 40;
  int tok = idx / 160;
  int s = tok & (SEQ - 1);
  float scale = (hh < 32) ? 0.125f * LOG2E : 1.0f;
  ushort* p = t + (size_t)tok * QKV_LD + hh * 64 + g * 8;
  union { uint4 v; ushort u[8]; } lo, hi, olo, ohi;
  lo.v = *(const uint4*)p;
  hi.v = *(const uint4*)(p + 32);
  const float* fcb = fc + s * HDIM + g * 8;
  const float* fsb = fs + s * HDIM + g * 8;
  float4 c0a = ((const float4*)fcb)[0], c0b = ((const float4*)fcb)[1];
  float4 s0a = ((const float4*)fsb)[0], s0b = ((const float4*)fsb)[1];
  float4 c1a = ((const float4*)(fcb + 32))[0], c1b = ((const float4*)(fcb + 32))[1];
  float4 s1a = ((const float4*)(fsb + 32))[0], s1b = ((const float4*)(fsb + 32))[1];
  float cc0[8] = {c0a.x, c0a.y, c0a.z, c0a.w, c0b.x, c0b.y, c0b.z, c0b.w};
  float ss0[8] = {s0a.x, s0a.y, s0a.z, s0a.w, s0b.x, s0b.y, s0b.z, s0b.w};
  float cc1[8] = {c1a.x, c1a.y, c1a.z, c1a.w, c1b.x, c1b.y, c1b.z, c1b.w};
  float ss1[8] = {s1a.x, s1a.y, s1a.z, s1a.w, s1b.x, s1b.y, s1b.z, s1b.w};
#pragma unroll
  for (int j = 0; j < 8; j++) {
    float x0 = bf2f(lo.u[j]), x1 = bf2f(hi.u[j]);
    olo.u[j] = f2bf((x0 * cc0[j] - x1 * ss0[j]) * scale);
    ohi.u[j] = f2bf((x1 * cc1[j] + x0 * ss1[j]) * scale);
  }
  *(uint4*)p = olo.v;
  *(uint4*)(p + 32) = ohi.v;
}

// ---------------- MFMA flash attention, transposed-S, exp2 domain ----------------
__global__ __launch_bounds__(256) void attn_mfma(const ushort* __restrict__ QKV,
                                                 ushort* __restrict__ O) {
  __shared__ ushort Ks[64][72];     // [key][d]
  __shared__ ushort Vt[64][72];     // [d][key]
  __shared__ ushort Pw[4][16][72];  // per-wave P[q][key]
  const int tid = threadIdx.x;
  const int lane = tid & 63, wave = tid >> 6;
  const int quad = lane >> 4, l16 = lane & 15;
  const int bh = blockIdx.y;
  const int b = bh >> 5, h = bh & 31, kh = h >> 2;
  const int p = blockIdx.x;
  const int qt[2] = {p, 31 - p};
  const int ntiles = 32 - p;

  short8 qf[2][2];
#pragma unroll
  for (int u = 0; u < 2; u++)
#pragma unroll
    for (int c = 0; c < 2; c++)
      qf[u][c] = *(const short8*)(QKV +
          (size_t)(b * SEQ + qt[u] * 64 + wave * 16 + l16) * QKV_LD +
          h * HDIM + c * 32 + quad * 8);

  f32x4 o[2][4] = {};
  float m[2] = {-INFINITY, -INFINITY}, l[2] = {0.f, 0.f};

  const ushort* Kbase = QKV + (size_t)b * SEQ * QKV_LD + 2048 + kh * HDIM;
  const ushort* Vbase = Kbase + 512;
  const int kp = tid & 31, dg = tid >> 5;
  const int relrow = wave * 16 + l16;

  for (int t = 0; t < ntiles; t++) {
    const int k0 = t * 64;
    __syncthreads();
    {
      const float4* kpp = (const float4*)(Kbase + (size_t)(k0 + lane) * QKV_LD + wave * 16);
      float4 kv0 = kpp[0], kv1 = kpp[1];
      const uint4* va4 = (const uint4*)(Vbase + (size_t)(k0 + 2 * kp) * QKV_LD + dg * 8);
      const uint4* vb4 = (const uint4*)(Vbase + (size_t)(k0 + 2 * kp + 1) * QKV_LD + dg * 8);
      uint4 va = va4[0], vb = vb4[0];
      *(float4*)&Ks[lane][wave * 16] = kv0;
      *(float4*)&Ks[lane][wave * 16 + 8] = kv1;
      const unsigned* vaw = (const unsigned*)&va;
      const unsigned* vbw = (const unsigned*)&vb;
#pragma unroll
      for (int j = 0; j < 8; j++) {
        unsigned pk = (j & 1)
            ? __builtin_amdgcn_perm(vbw[j >> 1], vaw[j >> 1], 0x07060302)
            : __builtin_amdgcn_perm(vbw[j >> 1], vaw[j >> 1], 0x05040100);
        *(unsigned*)&Vt[dg * 8 + j][2 * kp] = pk;
      }
    }
    __syncthreads();

#pragma unroll
    for (int u = 0; u < 2; u++) {
      const int diag = qt[u];
      if (t > diag) continue;

      f32x4 s[4];
#pragma unroll
      for (int nt = 0; nt < 4; nt++) {
        short8 kf0 = *(short8*)&Ks[nt * 16 + l16][quad * 8];
        short8 kf1 = *(short8*)&Ks[nt * 16 + l16][32 + quad * 8];
        f32x4 z = {};
        z = __builtin_amdgcn_mfma_f32_16x16x32_bf16(kf0, qf[u][0], z, 0, 0, 0);
        s[nt] = __builtin_amdgcn_mfma_f32_16x16x32_bf16(kf1, qf[u][1], z, 0, 0, 0);
      }

      if (t == diag) {
#pragma unroll
        for (int nt = 0; nt < 4; nt++)
#pragma unroll
          for (int r = 0; r < 4; r++)
            if (nt * 16 + quad * 4 + r > relrow) s[nt][r] = -INFINITY;
      }

      float mx = -INFINITY;
#pragma unroll
      for (int nt = 0; nt < 4; nt++)
#pragma unroll
        for (int r = 0; r < 4; r++) mx = fmaxf(mx, s[nt][r]);
      mx = fmaxf(mx, __shfl_xor(mx, 16));
      mx = fmaxf(mx, __shfl_xor(mx, 32));
      float mnew = fmaxf(m[u], mx);
      float al = hw_exp2(m[u] - mnew);  // exp2 domain (log2e folded into Q)
      m[u] = mnew;

      float pv[16];
      float psum = 0.f;
#pragma unroll
      for (int nt = 0; nt < 4; nt++)
#pragma unroll
        for (int r = 0; r < 4; r++) {
          float pe = hw_exp2(s[nt][r] - mnew);
          pv[nt * 4 + r] = pe;
          psum += pe;
        }
      psum += __shfl_xor(psum, 16);
      psum += __shfl_xor(psum, 32);
      l[u] = l[u] * al + psum;
#pragma unroll
      for (int dt = 0; dt < 4; dt++)
#pragma unroll
        for (int r = 0; r < 4; r++) o[u][dt][r] *= al;

#pragma unroll
      for (int nt = 0; nt < 4; nt++) {
        unsigned lo = __builtin_amdgcn_perm(fbits(pv[nt * 4 + 1]), fbits(pv[nt * 4 + 0]), 0x07060302);
        unsigned hi = __builtin_amdgcn_perm(fbits(pv[nt * 4 + 3]), fbits(pv[nt * 4 + 2]), 0x07060302);
        uint2 pk; pk.x = lo; pk.y = hi;
        *(uint2*)&Pw[wave][l16][nt * 16 + quad * 4] = pk;
      }
      short8 pf0 = *(short8*)&Pw[wave][l16][quad * 8];
      short8 pf1 = *(short8*)&Pw[wave][l16][32 + quad * 8];
#pragma unroll
      for (int dt = 0; dt < 4; dt++) {
        short8 vf0 = *(short8*)&Vt[dt * 16 + l16][quad * 8];
        short8 vf1 = *(short8*)&Vt[dt * 16 + l16][32 + quad * 8];
        o[u][dt] = __builtin_amdgcn_mfma_f32_16x16x32_bf16(vf0, pf0, o[u][dt], 0, 0, 0);
        o[u][dt] = __builtin_amdgcn_mfma_f32_16x16x32_bf16(vf1, pf1, o[u][dt], 0, 0, 0);
      }
    }
  }

#pragma unroll
  for (int u = 0; u < 2; u++) {
    float inv = 1.0f / l[u];
    size_t rowg = (size_t)(b * SEQ + qt[u] * 64 + wave * 16 + l16) * EMBED + h * HDIM;
#pragma unroll
    for (int dt = 0; dt < 4; dt++) {
      ushort q0 = f2bf(o[u][dt][0] * inv), q1 = f2bf(o[u][dt][1] * inv);
      ushort q2 = f2bf(o[u][dt][2] * inv), q3 = f2bf(o[u][dt][3] * inv);
      uint2 pk;
      pk.x = (unsigned)q0 | ((unsigned)q1 << 16);
      pk.y = (unsigned)q2 | ((unsigned)q3 << 16);
      *(uint2*)&O[rowg + dt * 16 + quad * 4] = pk;
    }
  }
}

// ---------------- launch ----------------
extern "C" void kernel_launch(void* const* d_in, const int* in_sizes, int n_in,
                              void* d_out, int out_size, void* d_ws, size_t ws_size,
                              hipStream_t stream) {
  const float* x = (const float*)d_in[0];
  const float* fcos = (const float*)d_in[1];
  const float* fsin = (const float*)d_in[2];
  const float* wq = (const float*)d_in[3];
  const float* wk = (const float*)d_in[4];
  const float* wv = (const float*)d_in[5];
  const float* wo = (const float*)d_in[6];
  float* out = (float*)d_out;

  const int M = BATCH * SEQ;  // 4096
  ushort* ws = (ushort*)d_ws;
  ushort* xb = ws;
  ushort* wqkv = xb + (size_t)M * EMBED;
  ushort* wob = wqkv + (size_t)QKV_LD * EMBED;
  ushort* QKVb = wob + (size_t)EMBED * EMBED;
  ushort* Ab = QKVb + (size_t)M * QKV_LD;

  dim3 blk(256);
  // all conversions in one launch: 18874368 elems / 8 per thread / 256
  cvt_all<<<9216, blk, 0, stream>>>(x, wq, wk, wv, wo, xb, wqkv, wob);

  gemm_bf16<ushort><<<dim3(QKV_LD / 128, M / 128), blk, 0, stream>>>(xb, wqkv, QKVb, M, QKV_LD, EMBED);

  {
    int tot = M * 40 * 4;  // 655360 threads, 16 dims per thread
    rope_qk<<<(tot + 255) / 256, blk, 0, stream>>>(QKVb, fcos, fsin, tot);
  }

  attn_mfma<<<dim3(16, BATCH * NHEADS), blk, 0, stream>>>(QKVb, Ab);

  gemm_bf16<float><<<dim3(EMBED / 128, M / 128), blk, 0, stream>>>(Ab, wob, out, M, EMBED, EMBED);
}